// Round 7
// baseline (6519.335 us; speedup 1.0000x reference)
//
#include <hip/hip_runtime.h>
#include <stdint.h>

// ---------------- problem constants ----------------
#define EDIM   300      // hidden/embed dim
#define KPAD   320      // padded K for MFMA GEMMs
#define NG     1200     // 4*EDIM gates
#define NB     64       // batch
#define SENC   64       // encoder steps
#define SDEC   63       // decoder steps
#define ZHV    12016
#define DROWS  4032     // NB*SDEC
#define MPAD   4096

typedef unsigned short u16;
typedef __attribute__((ext_vector_type(8))) short bf16x8;
typedef __attribute__((ext_vector_type(4))) float f32x4;

static __device__ __forceinline__ u16 f2bf(float f){
  uint32_t u = __builtin_bit_cast(uint32_t, f);
  return (u16)((u + 0x7fffu + ((u >> 16) & 1u)) >> 16);
}
static __device__ __forceinline__ float sigm(float x){ return 1.f/(1.f + __expf(-x)); }
static __device__ __forceinline__ float tanhf_(float x){
  x = fminf(fmaxf(x, -15.f), 15.f);
  float e = __expf(2.f*x);
  return (e - 1.f)/(e + 1.f);
}

// ---------------- workspace init ----------------
__global__ void zero_kernel(float4* p, long n){
  long i = (long)blockIdx.x*blockDim.x + threadIdx.x;
  long st = (long)gridDim.x*blockDim.x;
  float4 z = {0.f,0.f,0.f,0.f};
  for (; i < n; i += st) p[i] = z;
}

// ---------------- Whh (1200x300) f32 -> MFMA A-fragment tiles bf16 ----------------
// frag = ((slice*4 + gate)*10 + kc); elem (lane*8 + e) = Whh[g*300 + slice*16 + (lane&15)]
//                                                          [kc*32 + (lane>>4)*8 + e], 0-padded.
__global__ void build_wa(const float* __restrict__ W, u16* __restrict__ out){
  int idx = blockIdx.x*blockDim.x + threadIdx.x;
  if (idx >= 20*4*10*512) return;
  int e    = idx & 7;
  int lane = (idx >> 3) & 63;
  int frag = idx >> 9;
  int kc = frag % 10;
  int g  = (frag / 10) & 3;
  int s  = frag / 40;
  int j = s*16 + (lane & 15);
  int k = kc*32 + ((lane >> 4) << 3) + e;
  float f = (j < EDIM && k < EDIM) ? W[(size_t)(g*EDIM + j)*EDIM + k] : 0.f;
  out[idx] = f2bf(f);
}

// ---------------- weight repack: (N x 300) f32 -> (Npad x 320) bf16 ----------------
__global__ void build_b(const float* __restrict__ W, u16* __restrict__ out, int N){
  int idx = blockIdx.x*blockDim.x + threadIdx.x;
  if (idx >= N*EDIM) return;
  int n = idx / EDIM, k = idx - n*EDIM;
  out[(size_t)n*KPAD + k] = f2bf(W[idx]);
}

// ---------------- embeddings -> padded bf16 A operands ----------------
__global__ void embed_en(const int* __restrict__ ids, const float* __restrict__ emb, u16* __restrict__ x){
  int idx = blockIdx.x*blockDim.x + threadIdx.x;
  if (idx >= MPAD*EDIM) return;
  int r = idx / EDIM, k = idx - r*EDIM;
  x[(size_t)r*KPAD + k] = f2bf(emb[(size_t)ids[r]*EDIM + k]);
}
__global__ void embed_zh(const int* __restrict__ zh, const float* __restrict__ emb, u16* __restrict__ x){
  int idx = blockIdx.x*blockDim.x + threadIdx.x;
  if (idx >= DROWS*EDIM) return;
  int r = idx / EDIM, k = idx - r*EDIM;
  int b = r / SDEC, t = r - b*SDEC;
  x[(size_t)r*KPAD + k] = f2bf(emb[(size_t)zh[b*SENC + t]*EDIM + k]);
}

// ---------------- bf16 MFMA GEMM: C[m,n] = sum_k A[m,k]*B[n,k] (+bias[n]) ----------------
#define LDT 40   // LDS row stride in bf16 elems (80 B)
__global__ __launch_bounds__(256) void gemm_nt(const u16* __restrict__ A, const u16* __restrict__ B,
                float* __restrict__ C, int ldc, int Mreal, int Nreal, const float* __restrict__ bias){
  __shared__ __align__(16) u16 As[128*LDT];
  __shared__ __align__(16) u16 Bs[128*LDT];
  int tid = threadIdx.x;
  int lane = tid & 63, wave = tid >> 6;
  int wm = wave >> 1, wn = wave & 1;
  int m0 = blockIdx.y*128, n0 = blockIdx.x*128;
  f32x4 acc[4][4];
  for (int i=0;i<4;i++) for (int j=0;j<4;j++) acc[i][j] = (f32x4){0.f,0.f,0.f,0.f};
  int r16 = lane & 15, kg = lane >> 4;
  for (int kt=0; kt<KPAD/32; kt++){
    int k0 = kt*32;
    for (int c=0;c<2;c++){
      int id = c*256 + tid;            // 0..511
      int row = id >> 2, col = id & 3; // 4 x 16B chunks per 32-k row
      *(uint4*)&As[row*LDT + col*8] = *(const uint4*)&A[(size_t)(m0+row)*KPAD + k0 + col*8];
      *(uint4*)&Bs[row*LDT + col*8] = *(const uint4*)&B[(size_t)(n0+row)*KPAD + k0 + col*8];
    }
    __syncthreads();
    bf16x8 af[4], bfr[4];
    for (int i=0;i<4;i++) af[i]  = *(const bf16x8*)&As[(wm*64 + i*16 + r16)*LDT + kg*8];
    for (int j=0;j<4;j++) bfr[j] = *(const bf16x8*)&Bs[(wn*64 + j*16 + r16)*LDT + kg*8];
    for (int i=0;i<4;i++)
      for (int j=0;j<4;j++)
        acc[i][j] = __builtin_amdgcn_mfma_f32_16x16x32_bf16(af[i], bfr[j], acc[i][j], 0, 0, 0);
    __syncthreads();
  }
  // C/D layout (m89-verified): col = lane&15, row = (lane>>4)*4 + reg
  for (int j=0;j<4;j++){
    int col = n0 + wn*64 + j*16 + r16;
    if (col >= Nreal) continue;
    float bv = bias ? bias[col] : 0.f;
    for (int i=0;i<4;i++){
      int rbase = m0 + wm*64 + i*16 + kg*4;
      for (int r=0;r<4;r++){
        int row = rbase + r;
        if (row < Mreal) C[(size_t)row*ldc + col] = acc[i][j][r] + bv;
      }
    }
  }
}

// ---------------- LSTM recurrence: row-parallel, zero inter-block communication ----------------
// The recurrence is independent per batch row. 4 blocks x 1024 threads (16 waves);
// block rg owns rows [rg*16, rg*16+16) for the WHOLE sequence. Whh lives entirely in
// VGPRs (wave w: slice w = j [16w,16w+16) x 4 gates; waves 0-2 also own slices 16-18;
// slice 19 is pure padding). 16 rows = exactly one 16x16x32 B-tile, so per step:
// XIH f32x4 fragment loads (L3, hidden under compute) -> 40-80 MFMA/wave from
// LDS-resident h -> lane-local activation (C layout: col=batch row, row=j) ->
// h(t) to the other LDS buffer -> ONE __syncthreads. No atomics, no flags, no fences.
__global__ __launch_bounds__(1024,1) void recur4(
    const float* __restrict__ Xih, const u16* __restrict__ WA,
    const float* __restrict__ h0, const float* __restrict__ c0,
    u16* seq, float* hfin, float* cfin, int steps)
{
  int tid = threadIdx.x;
  int lane = tid & 63, w = tid >> 6;
  int rg = blockIdx.x;
  int l15 = lane & 15, lk = lane >> 4;
  int row = rg*16 + l15;             // this lane's batch row (acc/act view)
  bool two = (w < 3);
  int s0 = w, s1 = 16 + w;
  int j0 = s0*16 + lk*4;             // always < 256 (real)
  int j1 = s1*16 + lk*4;             // 256..303 (mask >= 300)

  __shared__ __align__(16) u16 hb[2][16*320];   // h double buffer, XOR-swizzled rows

  // resident Whh A-fragments
  bf16x8 wf0[4][10], wf1[4][10];
  #pragma unroll
  for (int g=0; g<4; ++g)
    #pragma unroll
    for (int kc=0; kc<10; ++kc)
      wf0[g][kc] = *(const bf16x8*)&WA[(size_t)((s0*4+g)*10+kc)*512 + lane*8];
  if (two){
    #pragma unroll
    for (int g=0; g<4; ++g)
      #pragma unroll
      for (int kc=0; kc<10; ++kc)
        wf1[g][kc] = *(const bf16x8*)&WA[(size_t)((s1*4+g)*10+kc)*512 + lane*8];
  }

  // c state (lane-local forever)
  f32x4 cv0 = *(const f32x4*)&c0[row*EDIM + j0];
  f32x4 cv1 = (f32x4){0.f,0.f,0.f,0.f};
  if (two && j1 < EDIM) cv1 = *(const f32x4*)&c0[row*EDIM + j1];

  // zero both h buffers (k-pad must stay 0), then stage h0 into buffer 0
  for (int i=tid; i<2*16*160; i+=1024) ((uint32_t*)hb)[i] = 0;
  __syncthreads();
  for (int i=tid; i<16*150; i+=1024){
    int rw = i/150, jp = i - rw*150;               // j = 2jp, 2jp+1 (<300)
    float a = h0[(size_t)(rg*16+rw)*EDIM + jp*2];
    float b = h0[(size_t)(rg*16+rw)*EDIM + jp*2 + 1];
    uint32_t pk = (uint32_t)f2bf(a) | ((uint32_t)f2bf(b) << 16);
    *(uint32_t*)((char*)hb + rw*640 + ((jp*4) ^ ((rw&7)<<4))) = pk;
  }
  __syncthreads();

  for (int t=0; t<steps; ++t){
    int cur = t & 1;
    const char* hcur = (const char*)hb + cur*10240;
    char* hnxt = (char*)hb + (cur^1)*10240;

    // XIH fragment loads (f32x4; bias folded by gemm). Issued first, consumed post-MFMA.
    const float* xr = Xih + (size_t)(row*steps + t)*NG;
    f32x4 x0[4], x1[4];
    #pragma unroll
    for (int g=0; g<4; ++g) x0[g] = *(const f32x4*)&xr[g*EDIM + j0];
    if (two){
      #pragma unroll
      for (int g=0; g<4; ++g) x1[g] = *(const f32x4*)&xr[g*EDIM + j1];  // +64f ws pad covers overread
    }

    // gates = Whh x h(t-1): h B-frag from LDS, weights from registers
    f32x4 a0[4], a1[4];
    #pragma unroll
    for (int g=0; g<4; ++g){ a0[g] = (f32x4){0.f,0.f,0.f,0.f}; a1[g] = (f32x4){0.f,0.f,0.f,0.f}; }
    #pragma unroll
    for (int kc=0; kc<10; ++kc){
      bf16x8 hf = *(const bf16x8*)(hcur + l15*640 + ((kc*64 + lk*16) ^ ((l15&7)<<4)));
      #pragma unroll
      for (int g=0; g<4; ++g)
        a0[g] = __builtin_amdgcn_mfma_f32_16x16x32_bf16(wf0[g][kc], hf, a0[g], 0, 0, 0);
      if (two){
        #pragma unroll
        for (int g=0; g<4; ++g)
          a1[g] = __builtin_amdgcn_mfma_f32_16x16x32_bf16(wf1[g][kc], hf, a1[g], 0, 0, 0);
      }
    }

    // activation slice 0 (all lane-local)
    float hv[4];
    #pragma unroll
    for (int r=0;r<4;++r){
      float gi = a0[0][r]+x0[0][r], gf = a0[1][r]+x0[1][r];
      float gg = a0[2][r]+x0[2][r], go = a0[3][r]+x0[3][r];
      float c = sigm(gf)*cv0[r] + sigm(gi)*tanhf_(gg);
      cv0[r] = c;
      hv[r] = sigm(go)*tanhf_(c);
    }
    uint2 q0;
    q0.x = (uint32_t)f2bf(hv[0]) | ((uint32_t)f2bf(hv[1])<<16);
    q0.y = (uint32_t)f2bf(hv[2]) | ((uint32_t)f2bf(hv[3])<<16);
    *(uint2*)(hnxt + l15*640 + ((s0*32 + lk*8) ^ ((l15&7)<<4))) = q0;
    if (seq) *(uint2*)&seq[(size_t)(row*steps+t)*KPAD + j0] = q0;
    if (t == steps-1 && hfin){
      *(f32x4*)&hfin[row*EDIM + j0] = (f32x4){hv[0],hv[1],hv[2],hv[3]};
      *(f32x4*)&cfin[row*EDIM + j0] = cv0;
    }
    // activation slice 1 (waves 0-2)
    if (two){
      #pragma unroll
      for (int r=0;r<4;++r){
        float gi = a1[0][r]+x1[0][r], gf = a1[1][r]+x1[1][r];
        float gg = a1[2][r]+x1[2][r], go = a1[3][r]+x1[3][r];
        float c = sigm(gf)*cv1[r] + sigm(gi)*tanhf_(gg);
        cv1[r] = c;
        hv[r] = sigm(go)*tanhf_(c);
      }
      if (j1 < EDIM){   // j1 multiple of 4; <300 means whole quad real
        uint2 q1;
        q1.x = (uint32_t)f2bf(hv[0]) | ((uint32_t)f2bf(hv[1])<<16);
        q1.y = (uint32_t)f2bf(hv[2]) | ((uint32_t)f2bf(hv[3])<<16);
        *(uint2*)(hnxt + l15*640 + ((s1*32 + lk*8) ^ ((l15&7)<<4))) = q1;
        if (seq) *(uint2*)&seq[(size_t)(row*steps+t)*KPAD + j1] = q1;
        if (t == steps-1 && hfin){
          *(f32x4*)&hfin[row*EDIM + j1] = (f32x4){hv[0],hv[1],hv[2],hv[3]};
          *(f32x4*)&cfin[row*EDIM + j1] = cv1;
        }
      }
    }
    __syncthreads();   // h(t) complete in hnxt before anyone's next-step MFMA reads it
  }
}

// ---------------- fused log_softmax (in-place on d_out) + masked NLL ----------------
__global__ __launch_bounds__(256) void lsm_loss(float* __restrict__ out, const int* __restrict__ zh,
                                                float* __restrict__ lacc){
  int row = blockIdx.x;
  int tid = threadIdx.x;
  __shared__ float buf[ZHV];
  __shared__ float red[8];
  float* p = out + (size_t)row*ZHV;
  float m = -1e30f;
  for (int i=tid; i<ZHV; i+=256){ float v = p[i]; buf[i] = v; m = fmaxf(m, v); }
  for (int off=32; off; off>>=1) m = fmaxf(m, __shfl_xor(m, off));
  if ((tid&63)==0) red[tid>>6] = m;
  __syncthreads();
  m = fmaxf(fmaxf(red[0],red[1]), fmaxf(red[2],red[3]));
  float s = 0.f;
  for (int i=tid; i<ZHV; i+=256) s += __expf(buf[i]-m);
  for (int off=32; off; off>>=1) s += __shfl_xor(s, off);
  if ((tid&63)==0) red[4+(tid>>6)] = s;
  __syncthreads();
  s = red[4]+red[5]+red[6]+red[7];
  float lse = m + __logf(s);
  for (int i=tid; i<ZHV; i+=256) p[i] = buf[i] - lse;
  if (tid == 0){
    int b = row / SDEC, t = row - b*SDEC;
    int tgt = zh[b*SENC + t + 1];
    if (tgt != 0){
      atomicAdd(&lacc[0], -(buf[tgt] - lse));
      atomicAdd(&lacc[1], 1.0f);
    }
  }
}

__global__ void fin_loss(float* out, const float* lacc){
  out[(size_t)DROWS*ZHV] = lacc[0]/lacc[1];
}

// ---------------- host ----------------
extern "C" void kernel_launch(void* const* d_in, const int* in_sizes, int n_in,
                              void* d_out, int out_size, void* d_ws, size_t ws_size,
                              hipStream_t stream){
  const int*   en_in   = (const int*)d_in[0];
  const int*   zh_in   = (const int*)d_in[1];
  const float* en_emb  = (const float*)d_in[2];
  const float* zh_emb  = (const float*)d_in[3];
  const float* enc_Wih = (const float*)d_in[4];
  const float* enc_Whh = (const float*)d_in[5];
  const float* enc_b   = (const float*)d_in[6];
  const float* dec_Wih = (const float*)d_in[7];
  const float* dec_Whh = (const float*)d_in[8];
  const float* dec_b   = (const float*)d_in[9];
  const float* fc_W    = (const float*)d_in[10];
  const float* fc_b    = (const float*)d_in[11];
  float* out = (float*)d_out;
  char* ws = (char*)d_ws;

  size_t o = 0;
  auto alloc = [&](size_t b){ size_t r = o; o = (o + b + 255) & ~(size_t)255; return r; };
  size_t wa[4], wih[4];
  for (int i=0;i<4;i++) wa[i]  = alloc((size_t)20*4*10*512*2); // MFMA A-frag Whh bf16
  for (int i=0;i<4;i++) wih[i] = alloc((size_t)1280*KPAD*2);   // Wih as B operand
  size_t fcw  = alloc((size_t)12032*KPAD*2);
  size_t xen  = alloc((size_t)MPAD*KPAD*2);
  size_t xl1e = alloc((size_t)MPAD*KPAD*2);
  size_t xzh  = alloc((size_t)MPAD*KPAD*2);
  size_t xl1d = alloc((size_t)MPAD*KPAD*2);
  size_t xl2d = alloc((size_t)MPAD*KPAD*2);
  size_t xih  = alloc(((size_t)MPAD*NG + 64)*4);   // +64 floats: padded-slice overread
  size_t hfin = alloc((size_t)2*NB*EDIM*4);
  size_t cfin = alloc((size_t)2*NB*EDIM*4);
  size_t hz   = alloc((size_t)NB*EDIM*4 + 64);
  size_t lac  = alloc(256);
  size_t used = o;
  if (ws_size < used) return;  // fail loudly (output stays poisoned)

  zero_kernel<<<2048,256,0,stream>>>((float4*)ws, (long)(used/16));

  for (int l=0;l<2;l++){
    build_wa<<<1600,256,0,stream>>>(enc_Whh + (size_t)l*NG*EDIM, (u16*)(ws+wa[l]));
    build_wa<<<1600,256,0,stream>>>(dec_Whh + (size_t)l*NG*EDIM, (u16*)(ws+wa[2+l]));
    build_b<<<1407,256,0,stream>>>(enc_Wih + (size_t)l*NG*EDIM, (u16*)(ws+wih[l]),   NG);
    build_b<<<1407,256,0,stream>>>(dec_Wih + (size_t)l*NG*EDIM, (u16*)(ws+wih[2+l]), NG);
  }
  build_b<<<(ZHV*EDIM+255)/256,256,0,stream>>>(fc_W, (u16*)(ws+fcw), ZHV);
  embed_en<<<(MPAD*EDIM+255)/256,256,0,stream>>>(en_in, en_emb, (u16*)(ws+xen));
  embed_zh<<<(DROWS*EDIM+255)/256,256,0,stream>>>(zh_in, zh_emb, (u16*)(ws+xzh));

  float* XIH = (float*)(ws+xih);
  float* LAC = (float*)(ws+lac);
  float* HF  = (float*)(ws+hfin);
  float* CF  = (float*)(ws+cfin);
  float* HZ  = (float*)(ws+hz);

  // encoder layer 1  (LSTM bias folded into XIH via gemm bias)
  gemm_nt<<<dim3(10,32),256,0,stream>>>((u16*)(ws+xen), (u16*)(ws+wih[0]), XIH, NG, MPAD, NG, enc_b);
  recur4<<<4,1024,0,stream>>>(XIH, (u16*)(ws+wa[0]), HZ, HZ, (u16*)(ws+xl1e), HF, CF, SENC);
  // encoder layer 2 (hidden sequence unused; only finals kept)
  gemm_nt<<<dim3(10,32),256,0,stream>>>((u16*)(ws+xl1e), (u16*)(ws+wih[1]), XIH, NG, MPAD, NG, enc_b+NG);
  recur4<<<4,1024,0,stream>>>(XIH, (u16*)(ws+wa[1]), HZ, HZ, nullptr, HF+NB*EDIM, CF+NB*EDIM, SENC);
  // decoder layer 1
  gemm_nt<<<dim3(10,32),256,0,stream>>>((u16*)(ws+xzh), (u16*)(ws+wih[2]), XIH, NG, MPAD, NG, dec_b);
  recur4<<<4,1024,0,stream>>>(XIH, (u16*)(ws+wa[2]), HF, CF, (u16*)(ws+xl1d), nullptr, nullptr, SDEC);
  // decoder layer 2
  gemm_nt<<<dim3(10,32),256,0,stream>>>((u16*)(ws+xl1d), (u16*)(ws+wih[3]), XIH, NG, MPAD, NG, dec_b+NG);
  recur4<<<4,1024,0,stream>>>(XIH, (u16*)(ws+wa[3]), HF+NB*EDIM, CF+NB*EDIM, (u16*)(ws+xl2d), nullptr, nullptr, SDEC);
  // FC head -> logits straight into d_out
  gemm_nt<<<dim3(94,32),256,0,stream>>>((u16*)(ws+xl2d), (u16*)(ws+fcw), out, ZHV, DROWS, ZHV, fc_b);
  // in-place log_softmax + masked NLL
  lsm_loss<<<DROWS,256,0,stream>>>(out, zh_in, LAC);
  fin_loss<<<1,1,0,stream>>>(out, LAC);
}

// Round 8
// 5399.734 us; speedup vs baseline: 1.2073x; 1.2073x over previous
//
#include <hip/hip_runtime.h>
#include <stdint.h>

// ---------------- problem constants ----------------
#define EDIM   300      // hidden/embed dim
#define KPAD   320      // padded K for MFMA GEMMs
#define NG     1200     // 4*EDIM gates
#define NB     64       // batch
#define SENC   64       // encoder steps
#define SDEC   63       // decoder steps
#define ZHV    12016
#define DROWS  4032     // NB*SDEC
#define MPAD   4096

typedef unsigned short u16;
typedef __attribute__((ext_vector_type(8))) short bf16x8;
typedef __attribute__((ext_vector_type(4))) float f32x4;

static __device__ __forceinline__ u16 f2bf(float f){
  uint32_t u = __builtin_bit_cast(uint32_t, f);
  return (u16)((u + 0x7fffu + ((u >> 16) & 1u)) >> 16);
}
static __device__ __forceinline__ float sigm(float x){ return 1.f/(1.f + __expf(-x)); }
static __device__ __forceinline__ float tanhf_(float x){
  x = fminf(fmaxf(x, -15.f), 15.f);
  float e = __expf(2.f*x);
  return (e - 1.f)/(e + 1.f);
}

// ---------------- workspace init ----------------
__global__ void zero_kernel(float4* p, long n){
  long i = (long)blockIdx.x*blockDim.x + threadIdx.x;
  long st = (long)gridDim.x*blockDim.x;
  float4 z = {0.f,0.f,0.f,0.f};
  for (; i < n; i += st) p[i] = z;
}

// ---------------- Whh (1200x300) f32 -> MFMA A-fragment tiles bf16 ----------------
// frag = ((slice*4 + gate)*10 + kc); elem (lane*8 + e) = Whh[g*300 + slice*16 + (lane&15)]
//                                                          [kc*32 + (lane>>4)*8 + e], 0-padded.
__global__ void build_wa(const float* __restrict__ W, u16* __restrict__ out){
  int idx = blockIdx.x*blockDim.x + threadIdx.x;
  if (idx >= 20*4*10*512) return;
  int e    = idx & 7;
  int lane = (idx >> 3) & 63;
  int frag = idx >> 9;
  int kc = frag % 10;
  int g  = (frag / 10) & 3;
  int s  = frag / 40;
  int j = s*16 + (lane & 15);
  int k = kc*32 + ((lane >> 4) << 3) + e;
  float f = (j < EDIM && k < EDIM) ? W[(size_t)(g*EDIM + j)*EDIM + k] : 0.f;
  out[idx] = f2bf(f);
}

// ---------------- weight repack: (N x 300) f32 -> (Npad x 320) bf16 ----------------
__global__ void build_b(const float* __restrict__ W, u16* __restrict__ out, int N){
  int idx = blockIdx.x*blockDim.x + threadIdx.x;
  if (idx >= N*EDIM) return;
  int n = idx / EDIM, k = idx - n*EDIM;
  out[(size_t)n*KPAD + k] = f2bf(W[idx]);
}

// ---------------- embeddings -> padded bf16 A operands ----------------
__global__ void embed_en(const int* __restrict__ ids, const float* __restrict__ emb, u16* __restrict__ x){
  int idx = blockIdx.x*blockDim.x + threadIdx.x;
  if (idx >= MPAD*EDIM) return;
  int r = idx / EDIM, k = idx - r*EDIM;
  x[(size_t)r*KPAD + k] = f2bf(emb[(size_t)ids[r]*EDIM + k]);
}
__global__ void embed_zh(const int* __restrict__ zh, const float* __restrict__ emb, u16* __restrict__ x){
  int idx = blockIdx.x*blockDim.x + threadIdx.x;
  if (idx >= DROWS*EDIM) return;
  int r = idx / EDIM, k = idx - r*EDIM;
  int b = r / SDEC, t = r - b*SDEC;
  x[(size_t)r*KPAD + k] = f2bf(emb[(size_t)zh[b*SENC + t]*EDIM + k]);
}

// ---------------- bf16 MFMA GEMM: C[m,n] = sum_k A[m,k]*B[n,k] (+bias[n]) ----------------
#define LDT 40   // LDS row stride in bf16 elems (80 B)
__global__ __launch_bounds__(256) void gemm_nt(const u16* __restrict__ A, const u16* __restrict__ B,
                float* __restrict__ C, int ldc, int Mreal, int Nreal, const float* __restrict__ bias){
  __shared__ __align__(16) u16 As[128*LDT];
  __shared__ __align__(16) u16 Bs[128*LDT];
  int tid = threadIdx.x;
  int lane = tid & 63, wave = tid >> 6;
  int wm = wave >> 1, wn = wave & 1;
  int m0 = blockIdx.y*128, n0 = blockIdx.x*128;
  f32x4 acc[4][4];
  for (int i=0;i<4;i++) for (int j=0;j<4;j++) acc[i][j] = (f32x4){0.f,0.f,0.f,0.f};
  int r16 = lane & 15, kg = lane >> 4;
  for (int kt=0; kt<KPAD/32; kt++){
    int k0 = kt*32;
    for (int c=0;c<2;c++){
      int id = c*256 + tid;            // 0..511
      int row = id >> 2, col = id & 3; // 4 x 16B chunks per 32-k row
      *(uint4*)&As[row*LDT + col*8] = *(const uint4*)&A[(size_t)(m0+row)*KPAD + k0 + col*8];
      *(uint4*)&Bs[row*LDT + col*8] = *(const uint4*)&B[(size_t)(n0+row)*KPAD + k0 + col*8];
    }
    __syncthreads();
    bf16x8 af[4], bfr[4];
    for (int i=0;i<4;i++) af[i]  = *(const bf16x8*)&As[(wm*64 + i*16 + r16)*LDT + kg*8];
    for (int j=0;j<4;j++) bfr[j] = *(const bf16x8*)&Bs[(wn*64 + j*16 + r16)*LDT + kg*8];
    for (int i=0;i<4;i++)
      for (int j=0;j<4;j++)
        acc[i][j] = __builtin_amdgcn_mfma_f32_16x16x32_bf16(af[i], bfr[j], acc[i][j], 0, 0, 0);
    __syncthreads();
  }
  // C/D layout (m89-verified): col = lane&15, row = (lane>>4)*4 + reg
  for (int j=0;j<4;j++){
    int col = n0 + wn*64 + j*16 + r16;
    if (col >= Nreal) continue;
    float bv = bias ? bias[col] : 0.f;
    for (int i=0;i<4;i++){
      int rbase = m0 + wm*64 + i*16 + kg*4;
      for (int r=0;r<4;r++){
        int row = rbase + r;
        if (row < Mreal) C[(size_t)row*ldc + col] = acc[i][j][r] + bv;
      }
    }
  }
}

// ---------------- LSTM recurrence: row-parallel, spill-proof register plan ----------------
// 4 blocks x 1024 threads (16 waves, exactly 1 block/CU, 4 waves/EU). Block rg owns
// rows [rg*16, rg*16+16). Wave w keeps ONE slice (j [16w,16w+16) x 4 gates) in
// registers: 160 VGPR. The 3 overflow slices (16..18, j 256..303) live in LDS
// (120 KB, staged once); waves 0..2 read their fragments per step via ds_read_b128
// (lane-contiguous, conflict-free, hidden under MFMA). Peak demand ~280 VGPR < 512.
// h double-buffered in LDS (XOR-swizzled), ONE barrier/step, activation lane-local.
__global__ __launch_bounds__(1024,4) void recur4(
    const float* __restrict__ Xih, const u16* __restrict__ WA,
    const float* __restrict__ h0, const float* __restrict__ c0,
    u16* seq, float* hfin, float* cfin, int steps)
{
  int tid = threadIdx.x;
  int lane = tid & 63, w = tid >> 6;
  int rg = blockIdx.x;
  int l15 = lane & 15, lk = lane >> 4;
  int row = rg*16 + l15;             // this lane's batch row (acc/act view)
  bool two = (w < 3);
  int s0 = w, s1 = 16 + w;
  int j0 = s0*16 + lk*4;             // < 256, always real
  int j1 = s1*16 + lk*4;             // 256..300 (j1==300 masked)

  __shared__ __align__(16) u16 hb[2][16*320];      // h double buffer, XOR-swizzled rows
  __shared__ __align__(16) u16 wl[3][4][10][512];  // overflow slices 16..18 weights

  // stage overflow-slice weights into LDS (contiguous in WA: frags 640..759)
  {
    const uint4* src = (const uint4*)(WA + (size_t)640*512);
    for (int i = tid; i < 3*4*10*512/8; i += 1024)
      ((uint4*)wl)[i] = src[i];
  }

  // resident main-slice weights: 160 VGPR
  bf16x8 wf[4][10];
  #pragma unroll
  for (int g=0; g<4; ++g)
    #pragma unroll
    for (int kc=0; kc<10; ++kc)
      wf[g][kc] = *(const bf16x8*)&WA[(size_t)((s0*4+g)*10+kc)*512 + lane*8];

  // c state (lane-local forever)
  f32x4 cv0 = *(const f32x4*)&c0[row*EDIM + j0];
  f32x4 cv1 = (f32x4){0.f,0.f,0.f,0.f};
  if (two && j1 < EDIM) cv1 = *(const f32x4*)&c0[row*EDIM + j1];

  // zero both h buffers (k-pad must stay 0), then stage h0 into buffer 0
  for (int i=tid; i<2*16*160; i+=1024) ((uint32_t*)hb)[i] = 0;
  __syncthreads();
  for (int i=tid; i<16*150; i+=1024){
    int rw = i/150, jp = i - rw*150;               // j = 2jp, 2jp+1 (<300)
    float a = h0[(size_t)(rg*16+rw)*EDIM + jp*2];
    float b = h0[(size_t)(rg*16+rw)*EDIM + jp*2 + 1];
    uint32_t pk = (uint32_t)f2bf(a) | ((uint32_t)f2bf(b) << 16);
    *(uint32_t*)((char*)hb + rw*640 + ((jp*4) ^ ((rw&7)<<4))) = pk;
  }
  __syncthreads();

  for (int t=0; t<steps; ++t){
    int cur = t & 1;
    const char* hcur = (const char*)hb + cur*10240;
    char* hnxt = (char*)hb + (cur^1)*10240;

    // XIH fragment loads (f32x4; bias folded by gemm). Issued first, consumed post-MFMA.
    const float* xr = Xih + (size_t)(row*steps + t)*NG;
    f32x4 x0[4], x1[4];
    #pragma unroll
    for (int g=0; g<4; ++g) x0[g] = *(const f32x4*)&xr[g*EDIM + j0];
    if (two){
      #pragma unroll
      for (int g=0; g<4; ++g) x1[g] = *(const f32x4*)&xr[g*EDIM + j1];  // +64f ws pad covers overread
    }

    // gates = Whh x h(t-1): h B-frag from LDS, main weights from registers,
    // overflow-slice weights from LDS
    f32x4 a0[4], a1[4];
    #pragma unroll
    for (int g=0; g<4; ++g){ a0[g] = (f32x4){0.f,0.f,0.f,0.f}; a1[g] = (f32x4){0.f,0.f,0.f,0.f}; }
    #pragma unroll
    for (int kc=0; kc<10; ++kc){
      bf16x8 hf = *(const bf16x8*)(hcur + l15*640 + ((kc*64 + lk*16) ^ ((l15&7)<<4)));
      #pragma unroll
      for (int g=0; g<4; ++g)
        a0[g] = __builtin_amdgcn_mfma_f32_16x16x32_bf16(wf[g][kc], hf, a0[g], 0, 0, 0);
      if (two){
        #pragma unroll
        for (int g=0; g<4; ++g){
          bf16x8 wx = *(const bf16x8*)&wl[w][g][kc][lane*8];
          a1[g] = __builtin_amdgcn_mfma_f32_16x16x32_bf16(wx, hf, a1[g], 0, 0, 0);
        }
      }
    }

    // activation slice 0 (all lane-local)
    float hv[4];
    #pragma unroll
    for (int r=0;r<4;++r){
      float gi = a0[0][r]+x0[0][r], gf = a0[1][r]+x0[1][r];
      float gg = a0[2][r]+x0[2][r], go = a0[3][r]+x0[3][r];
      float c = sigm(gf)*cv0[r] + sigm(gi)*tanhf_(gg);
      cv0[r] = c;
      hv[r] = sigm(go)*tanhf_(c);
    }
    uint2 q0;
    q0.x = (uint32_t)f2bf(hv[0]) | ((uint32_t)f2bf(hv[1])<<16);
    q0.y = (uint32_t)f2bf(hv[2]) | ((uint32_t)f2bf(hv[3])<<16);
    *(uint2*)(hnxt + l15*640 + ((s0*32 + lk*8) ^ ((l15&7)<<4))) = q0;
    if (seq) *(uint2*)&seq[(size_t)(row*steps+t)*KPAD + j0] = q0;
    if (t == steps-1 && hfin){
      *(f32x4*)&hfin[row*EDIM + j0] = (f32x4){hv[0],hv[1],hv[2],hv[3]};
      *(f32x4*)&cfin[row*EDIM + j0] = cv0;
    }
    // activation slice 1 (waves 0-2)
    if (two){
      #pragma unroll
      for (int r=0;r<4;++r){
        float gi = a1[0][r]+x1[0][r], gf = a1[1][r]+x1[1][r];
        float gg = a1[2][r]+x1[2][r], go = a1[3][r]+x1[3][r];
        float c = sigm(gf)*cv1[r] + sigm(gi)*tanhf_(gg);
        cv1[r] = c;
        hv[r] = sigm(go)*tanhf_(c);
      }
      if (j1 < EDIM){   // j1 multiple of 4; <300 means whole quad real
        uint2 q1;
        q1.x = (uint32_t)f2bf(hv[0]) | ((uint32_t)f2bf(hv[1])<<16);
        q1.y = (uint32_t)f2bf(hv[2]) | ((uint32_t)f2bf(hv[3])<<16);
        *(uint2*)(hnxt + l15*640 + ((s1*32 + lk*8) ^ ((l15&7)<<4))) = q1;
        if (seq) *(uint2*)&seq[(size_t)(row*steps+t)*KPAD + j1] = q1;
        if (t == steps-1 && hfin){
          *(f32x4*)&hfin[row*EDIM + j1] = (f32x4){hv[0],hv[1],hv[2],hv[3]};
          *(f32x4*)&cfin[row*EDIM + j1] = cv1;
        }
      }
    }
    __syncthreads();   // h(t) complete in hnxt before anyone's next-step MFMA reads it
  }
}

// ---------------- fused log_softmax (in-place on d_out) + masked NLL ----------------
__global__ __launch_bounds__(256) void lsm_loss(float* __restrict__ out, const int* __restrict__ zh,
                                                float* __restrict__ lacc){
  int row = blockIdx.x;
  int tid = threadIdx.x;
  __shared__ float buf[ZHV];
  __shared__ float red[8];
  float* p = out + (size_t)row*ZHV;
  float m = -1e30f;
  for (int i=tid; i<ZHV; i+=256){ float v = p[i]; buf[i] = v; m = fmaxf(m, v); }
  for (int off=32; off; off>>=1) m = fmaxf(m, __shfl_xor(m, off));
  if ((tid&63)==0) red[tid>>6] = m;
  __syncthreads();
  m = fmaxf(fmaxf(red[0],red[1]), fmaxf(red[2],red[3]));
  float s = 0.f;
  for (int i=tid; i<ZHV; i+=256) s += __expf(buf[i]-m);
  for (int off=32; off; off>>=1) s += __shfl_xor(s, off);
  if ((tid&63)==0) red[4+(tid>>6)] = s;
  __syncthreads();
  s = red[4]+red[5]+red[6]+red[7];
  float lse = m + __logf(s);
  for (int i=tid; i<ZHV; i+=256) p[i] = buf[i] - lse;
  if (tid == 0){
    int b = row / SDEC, t = row - b*SDEC;
    int tgt = zh[b*SENC + t + 1];
    if (tgt != 0){
      atomicAdd(&lacc[0], -(buf[tgt] - lse));
      atomicAdd(&lacc[1], 1.0f);
    }
  }
}

__global__ void fin_loss(float* out, const float* lacc){
  out[(size_t)DROWS*ZHV] = lacc[0]/lacc[1];
}

// ---------------- host ----------------
extern "C" void kernel_launch(void* const* d_in, const int* in_sizes, int n_in,
                              void* d_out, int out_size, void* d_ws, size_t ws_size,
                              hipStream_t stream){
  const int*   en_in   = (const int*)d_in[0];
  const int*   zh_in   = (const int*)d_in[1];
  const float* en_emb  = (const float*)d_in[2];
  const float* zh_emb  = (const float*)d_in[3];
  const float* enc_Wih = (const float*)d_in[4];
  const float* enc_Whh = (const float*)d_in[5];
  const float* enc_b   = (const float*)d_in[6];
  const float* dec_Wih = (const float*)d_in[7];
  const float* dec_Whh = (const float*)d_in[8];
  const float* dec_b   = (const float*)d_in[9];
  const float* fc_W    = (const float*)d_in[10];
  const float* fc_b    = (const float*)d_in[11];
  float* out = (float*)d_out;
  char* ws = (char*)d_ws;

  size_t o = 0;
  auto alloc = [&](size_t b){ size_t r = o; o = (o + b + 255) & ~(size_t)255; return r; };
  size_t wa[4], wih[4];
  for (int i=0;i<4;i++) wa[i]  = alloc((size_t)20*4*10*512*2); // MFMA A-frag Whh bf16
  for (int i=0;i<4;i++) wih[i] = alloc((size_t)1280*KPAD*2);   // Wih as B operand
  size_t fcw  = alloc((size_t)12032*KPAD*2);
  size_t xen  = alloc((size_t)MPAD*KPAD*2);
  size_t xl1e = alloc((size_t)MPAD*KPAD*2);
  size_t xzh  = alloc((size_t)MPAD*KPAD*2);
  size_t xl1d = alloc((size_t)MPAD*KPAD*2);
  size_t xl2d = alloc((size_t)MPAD*KPAD*2);
  size_t xih  = alloc(((size_t)MPAD*NG + 64)*4);   // +64 floats: padded-slice overread
  size_t hfin = alloc((size_t)2*NB*EDIM*4);
  size_t cfin = alloc((size_t)2*NB*EDIM*4);
  size_t hz   = alloc((size_t)NB*EDIM*4 + 64);
  size_t lac  = alloc(256);
  size_t used = o;
  if (ws_size < used) return;  // fail loudly (output stays poisoned)

  zero_kernel<<<2048,256,0,stream>>>((float4*)ws, (long)(used/16));

  for (int l=0;l<2;l++){
    build_wa<<<1600,256,0,stream>>>(enc_Whh + (size_t)l*NG*EDIM, (u16*)(ws+wa[l]));
    build_wa<<<1600,256,0,stream>>>(dec_Whh + (size_t)l*NG*EDIM, (u16*)(ws+wa[2+l]));
    build_b<<<1407,256,0,stream>>>(enc_Wih + (size_t)l*NG*EDIM, (u16*)(ws+wih[l]),   NG);
    build_b<<<1407,256,0,stream>>>(dec_Wih + (size_t)l*NG*EDIM, (u16*)(ws+wih[2+l]), NG);
  }
  build_b<<<(ZHV*EDIM+255)/256,256,0,stream>>>(fc_W, (u16*)(ws+fcw), ZHV);
  embed_en<<<(MPAD*EDIM+255)/256,256,0,stream>>>(en_in, en_emb, (u16*)(ws+xen));
  embed_zh<<<(DROWS*EDIM+255)/256,256,0,stream>>>(zh_in, zh_emb, (u16*)(ws+xzh));

  float* XIH = (float*)(ws+xih);
  float* LAC = (float*)(ws+lac);
  float* HF  = (float*)(ws+hfin);
  float* CF  = (float*)(ws+cfin);
  float* HZ  = (float*)(ws+hz);

  // encoder layer 1  (LSTM bias folded into XIH via gemm bias)
  gemm_nt<<<dim3(10,32),256,0,stream>>>((u16*)(ws+xen), (u16*)(ws+wih[0]), XIH, NG, MPAD, NG, enc_b);
  recur4<<<4,1024,0,stream>>>(XIH, (u16*)(ws+wa[0]), HZ, HZ, (u16*)(ws+xl1e), HF, CF, SENC);
  // encoder layer 2 (hidden sequence unused; only finals kept)
  gemm_nt<<<dim3(10,32),256,0,stream>>>((u16*)(ws+xl1e), (u16*)(ws+wih[1]), XIH, NG, MPAD, NG, enc_b+NG);
  recur4<<<4,1024,0,stream>>>(XIH, (u16*)(ws+wa[1]), HZ, HZ, nullptr, HF+NB*EDIM, CF+NB*EDIM, SENC);
  // decoder layer 1
  gemm_nt<<<dim3(10,32),256,0,stream>>>((u16*)(ws+xzh), (u16*)(ws+wih[2]), XIH, NG, MPAD, NG, dec_b);
  recur4<<<4,1024,0,stream>>>(XIH, (u16*)(ws+wa[2]), HF, CF, (u16*)(ws+xl1d), nullptr, nullptr, SDEC);
  // decoder layer 2
  gemm_nt<<<dim3(10,32),256,0,stream>>>((u16*)(ws+xl1d), (u16*)(ws+wih[3]), XIH, NG, MPAD, NG, dec_b+NG);
  recur4<<<4,1024,0,stream>>>(XIH, (u16*)(ws+wa[3]), HF+NB*EDIM, CF+NB*EDIM, (u16*)(ws+xl2d), nullptr, nullptr, SDEC);
  // FC head -> logits straight into d_out
  gemm_nt<<<dim3(94,32),256,0,stream>>>((u16*)(ws+xl2d), (u16*)(ws+fcw), out, ZHV, DROWS, ZHV, fc_b);
  // in-place log_softmax + masked NLL
  lsm_loss<<<DROWS,256,0,stream>>>(out, zh_in, LAC);
  fin_loss<<<1,1,0,stream>>>(out, LAC);
}

// Round 9
// 3925.302 us; speedup vs baseline: 1.6608x; 1.3756x over previous
//
#include <hip/hip_runtime.h>
#include <stdint.h>

// ---------------- problem constants ----------------
#define EDIM   300      // hidden/embed dim
#define KPAD   320      // padded K for MFMA GEMMs
#define NG     1200     // 4*EDIM gates
#define NB     64       // batch
#define SENC   64       // encoder steps
#define SDEC   63       // decoder steps
#define ZHV    12016
#define DROWS  4032     // NB*SDEC
#define MPAD   4096

typedef unsigned short u16;
typedef __attribute__((ext_vector_type(8))) short bf16x8;
typedef __attribute__((ext_vector_type(4))) float f32x4;

static __device__ __forceinline__ u16 f2bf(float f){
  uint32_t u = __builtin_bit_cast(uint32_t, f);
  return (u16)((u + 0x7fffu + ((u >> 16) & 1u)) >> 16);
}
static __device__ __forceinline__ float sigm(float x){ return 1.f/(1.f + __expf(-x)); }
static __device__ __forceinline__ float tanhf_(float x){
  x = fminf(fmaxf(x, -15.f), 15.f);
  float e = __expf(2.f*x);
  return (e - 1.f)/(e + 1.f);
}

// ---------------- workspace init ----------------
__global__ void zero_kernel(float4* p, long n){
  long i = (long)blockIdx.x*blockDim.x + threadIdx.x;
  long st = (long)gridDim.x*blockDim.x;
  float4 z = {0.f,0.f,0.f,0.f};
  for (; i < n; i += st) p[i] = z;
}

// ---------------- Whh (1200x300) f32 -> MFMA A-fragment tiles bf16 ----------------
// frag = ((slice*4 + gate)*10 + kc); elem (lane*8 + e) = Whh[g*300 + slice*16 + (lane&15)]
//                                                          [kc*32 + (lane>>4)*8 + e], 0-padded.
__global__ void build_wa(const float* __restrict__ W, u16* __restrict__ out){
  int idx = blockIdx.x*blockDim.x + threadIdx.x;
  if (idx >= 20*4*10*512) return;
  int e    = idx & 7;
  int lane = (idx >> 3) & 63;
  int frag = idx >> 9;
  int kc = frag % 10;
  int g  = (frag / 10) & 3;
  int s  = frag / 40;
  int j = s*16 + (lane & 15);
  int k = kc*32 + ((lane >> 4) << 3) + e;
  float f = (j < EDIM && k < EDIM) ? W[(size_t)(g*EDIM + j)*EDIM + k] : 0.f;
  out[idx] = f2bf(f);
}

// ---------------- weight repack: (N x 300) f32 -> (Npad x 320) bf16 ----------------
__global__ void build_b(const float* __restrict__ W, u16* __restrict__ out, int N){
  int idx = blockIdx.x*blockDim.x + threadIdx.x;
  if (idx >= N*EDIM) return;
  int n = idx / EDIM, k = idx - n*EDIM;
  out[(size_t)n*KPAD + k] = f2bf(W[idx]);
}

// ---------------- embeddings -> padded bf16 A operands ----------------
__global__ void embed_en(const int* __restrict__ ids, const float* __restrict__ emb, u16* __restrict__ x){
  int idx = blockIdx.x*blockDim.x + threadIdx.x;
  if (idx >= MPAD*EDIM) return;
  int r = idx / EDIM, k = idx - r*EDIM;
  x[(size_t)r*KPAD + k] = f2bf(emb[(size_t)ids[r]*EDIM + k]);
}
__global__ void embed_zh(const int* __restrict__ zh, const float* __restrict__ emb, u16* __restrict__ x){
  int idx = blockIdx.x*blockDim.x + threadIdx.x;
  if (idx >= DROWS*EDIM) return;
  int r = idx / EDIM, k = idx - r*EDIM;
  int b = r / SDEC, t = r - b*SDEC;
  x[(size_t)r*KPAD + k] = f2bf(emb[(size_t)zh[b*SENC + t]*EDIM + k]);
}

// ---------------- bf16 MFMA GEMM: C[m,n] = sum_k A[m,k]*B[n,k] (+bias[n]) ----------------
#define LDT 40   // LDS row stride in bf16 elems (80 B)
__global__ __launch_bounds__(256) void gemm_nt(const u16* __restrict__ A, const u16* __restrict__ B,
                float* __restrict__ C, int ldc, int Mreal, int Nreal, const float* __restrict__ bias){
  __shared__ __align__(16) u16 As[128*LDT];
  __shared__ __align__(16) u16 Bs[128*LDT];
  int tid = threadIdx.x;
  int lane = tid & 63, wave = tid >> 6;
  int wm = wave >> 1, wn = wave & 1;
  int m0 = blockIdx.y*128, n0 = blockIdx.x*128;
  f32x4 acc[4][4];
  for (int i=0;i<4;i++) for (int j=0;j<4;j++) acc[i][j] = (f32x4){0.f,0.f,0.f,0.f};
  int r16 = lane & 15, kg = lane >> 4;
  for (int kt=0; kt<KPAD/32; kt++){
    int k0 = kt*32;
    for (int c=0;c<2;c++){
      int id = c*256 + tid;            // 0..511
      int row = id >> 2, col = id & 3; // 4 x 16B chunks per 32-k row
      *(uint4*)&As[row*LDT + col*8] = *(const uint4*)&A[(size_t)(m0+row)*KPAD + k0 + col*8];
      *(uint4*)&Bs[row*LDT + col*8] = *(const uint4*)&B[(size_t)(n0+row)*KPAD + k0 + col*8];
    }
    __syncthreads();
    bf16x8 af[4], bfr[4];
    for (int i=0;i<4;i++) af[i]  = *(const bf16x8*)&As[(wm*64 + i*16 + r16)*LDT + kg*8];
    for (int j=0;j<4;j++) bfr[j] = *(const bf16x8*)&Bs[(wn*64 + j*16 + r16)*LDT + kg*8];
    for (int i=0;i<4;i++)
      for (int j=0;j<4;j++)
        acc[i][j] = __builtin_amdgcn_mfma_f32_16x16x32_bf16(af[i], bfr[j], acc[i][j], 0, 0, 0);
    __syncthreads();
  }
  // C/D layout (m89-verified): col = lane&15, row = (lane>>4)*4 + reg
  for (int j=0;j<4;j++){
    int col = n0 + wn*64 + j*16 + r16;
    if (col >= Nreal) continue;
    float bv = bias ? bias[col] : 0.f;
    for (int i=0;i<4;i++){
      int rbase = m0 + wm*64 + i*16 + kg*4;
      for (int r=0;r<4;r++){
        int row = rbase + r;
        if (row < Mreal) C[(size_t)row*ldc + col] = acc[i][j][r] + bv;
      }
    }
  }
}

// ---------------- LSTM recurrence: row-parallel, 3-tier weight residency ----------------
// Capacity facts: CU regfile 512 KB < Whh 768 KB, so full register residency is
// impossible; LDS reads cost ~128 B/cy; L2 port ~144 GB/s/CU (the R3 5.3us/step wall).
// Plan: 4 blocks x 512 thr (8 waves, 1 block/CU, 2 waves/SIMD -> 256 VGPR cap).
// Block rg owns rows [16rg,16rg+16) — zero inter-block traffic, ONE barrier/step.
// Slices (16 j-outputs x 4 gates each): 0..7 register-resident (wave w holds slice w,
// 160 VGPR); 8..10 in LDS (120 KB, staged once); 11..18 streamed from L2 (320 KB/step,
// ~2.2us — the new, explicit bottleneck). Wave w computes slices {w, 11+w} (+ {8+w}
// for w<3), one at a time, acc reused, activation lane-local (C layout: col=row,
// row=j). h double-buffered in LDS, XOR-swizzled.
__global__ __launch_bounds__(512,2) void recur_mix(
    const float* __restrict__ Xih, const u16* __restrict__ WA,
    const float* __restrict__ h0, const float* __restrict__ c0,
    u16* seq, float* hfin, float* cfin, int steps)
{
  int tid = threadIdx.x;
  int lane = tid & 63, w = tid >> 6;
  int rg = blockIdx.x;
  int l15 = lane & 15, lk = lane >> 4;
  int row = rg*16 + l15;

  __shared__ __align__(16) u16 hb[2][16*320];      // h double buffer, XOR-swizzled rows
  __shared__ __align__(16) u16 wl[3][4][10][512];  // LDS slices 8..10

  // stage LDS weight slices (frags 320..439 are contiguous in WA)
  {
    const uint4* src = (const uint4*)(WA + (size_t)320*512);
    uint4* dst = (uint4*)wl;
    for (int i = tid; i < 7680; i += 512) dst[i] = src[i];
  }
  // zero both h buffers (pad k>=300 must stay 0)
  for (int i=tid; i<2*16*160; i+=512) ((uint32_t*)hb)[i] = 0;

  // resident slice w: 160 VGPR
  bf16x8 wf[4][10];
  #pragma unroll
  for (int g=0; g<4; ++g)
    #pragma unroll
    for (int kc=0; kc<10; ++kc)
      wf[g][kc] = *(const bf16x8*)&WA[(size_t)((w*4+g)*10+kc)*512 + lane*8];

  // per-slice j bases and c state (lane-local forever)
  int jR = w*16 + lk*4;          // < 128, always real
  int jS = (11+w)*16 + lk*4;     // 176..303 (j==300 masked)
  int jL = (8+w)*16 + lk*4;      // 128..175 (waves 0..2)
  f32x4 cR = *(const f32x4*)&c0[row*EDIM + jR];
  f32x4 cS = (f32x4){0.f,0.f,0.f,0.f};
  f32x4 cL = (f32x4){0.f,0.f,0.f,0.f};
  if (jS < EDIM) cS = *(const f32x4*)&c0[row*EDIM + jS];
  if (w < 3)     cL = *(const f32x4*)&c0[row*EDIM + jL];

  __syncthreads();
  // stage h0 into buffer 0
  for (int i=tid; i<16*150; i+=512){
    int rw = i/150, jp = i - rw*150;
    float a = h0[(size_t)(rg*16+rw)*EDIM + jp*2];
    float b = h0[(size_t)(rg*16+rw)*EDIM + jp*2 + 1];
    uint32_t pk = (uint32_t)f2bf(a) | ((uint32_t)f2bf(b) << 16);
    *(uint32_t*)((char*)hb + rw*640 + ((jp*4) ^ ((rw&7)<<4))) = pk;
  }
  __syncthreads();

  for (int t=0; t<steps; ++t){
    const char* hcur = (const char*)hb + (t&1)*10240;
    char* hnxt = (char*)hb + (((t&1)^1))*10240;
    const float* xr = Xih + (size_t)(row*steps + t)*NG;

    // helper: activation + publish for one slice (macro to keep regalloc simple)
#define ACT_PUB(ACC, CV, J)                                                        \
    {                                                                              \
      float hv0_, hv1_, hv2_, hv3_;                                                \
      { float c_ = sigm(ACC[1][0])*CV[0] + sigm(ACC[0][0])*tanhf_(ACC[2][0]);      \
        CV[0] = c_; hv0_ = sigm(ACC[3][0])*tanhf_(c_); }                           \
      { float c_ = sigm(ACC[1][1])*CV[1] + sigm(ACC[0][1])*tanhf_(ACC[2][1]);      \
        CV[1] = c_; hv1_ = sigm(ACC[3][1])*tanhf_(c_); }                           \
      { float c_ = sigm(ACC[1][2])*CV[2] + sigm(ACC[0][2])*tanhf_(ACC[2][2]);      \
        CV[2] = c_; hv2_ = sigm(ACC[3][2])*tanhf_(c_); }                           \
      { float c_ = sigm(ACC[1][3])*CV[3] + sigm(ACC[0][3])*tanhf_(ACC[2][3]);      \
        CV[3] = c_; hv3_ = sigm(ACC[3][3])*tanhf_(c_); }                           \
      if ((J) < EDIM){                                                             \
        uint2 q_;                                                                  \
        q_.x = (uint32_t)f2bf(hv0_) | ((uint32_t)f2bf(hv1_)<<16);                  \
        q_.y = (uint32_t)f2bf(hv2_) | ((uint32_t)f2bf(hv3_)<<16);                  \
        *(uint2*)(hnxt + l15*640 + (((J)*2) ^ ((l15&7)<<4))) = q_;                 \
        if (seq) *(uint2*)&seq[(size_t)(row*steps+t)*KPAD + (J)] = q_;             \
        if (t == steps-1 && hfin){                                                 \
          *(f32x4*)&hfin[row*EDIM + (J)] = (f32x4){hv0_,hv1_,hv2_,hv3_};           \
          *(f32x4*)&cfin[row*EDIM + (J)] = CV;                                     \
        }                                                                          \
      }                                                                            \
    }

    // ---- streamed slice (L2): issue its loads first, longest latency
    {
      int s = 11 + w;
      f32x4 acc[4];
      #pragma unroll
      for (int g=0; g<4; ++g) acc[g] = *(const f32x4*)&xr[g*EDIM + jS];
      const u16* wb = WA + (size_t)(s*40)*512 + lane*8;
      #pragma unroll
      for (int kc=0; kc<10; ++kc){
        bf16x8 hf = *(const bf16x8*)(hcur + l15*640 + (((kc*64) + lk*16) ^ ((l15&7)<<4)));
        #pragma unroll
        for (int g=0; g<4; ++g)
          acc[g] = __builtin_amdgcn_mfma_f32_16x16x32_bf16(
                     *(const bf16x8*)&wb[(size_t)(g*10+kc)*512], hf, acc[g], 0, 0, 0);
      }
      ACT_PUB(acc, cS, jS)
    }
    // ---- register-resident slice
    {
      f32x4 acc[4];
      #pragma unroll
      for (int g=0; g<4; ++g) acc[g] = *(const f32x4*)&xr[g*EDIM + jR];
      #pragma unroll
      for (int kc=0; kc<10; ++kc){
        bf16x8 hf = *(const bf16x8*)(hcur + l15*640 + (((kc*64) + lk*16) ^ ((l15&7)<<4)));
        #pragma unroll
        for (int g=0; g<4; ++g)
          acc[g] = __builtin_amdgcn_mfma_f32_16x16x32_bf16(wf[g][kc], hf, acc[g], 0, 0, 0);
      }
      ACT_PUB(acc, cR, jR)
    }
    // ---- LDS slice (waves 0..2)
    if (w < 3){
      f32x4 acc[4];
      #pragma unroll
      for (int g=0; g<4; ++g) acc[g] = *(const f32x4*)&xr[g*EDIM + jL];
      #pragma unroll
      for (int kc=0; kc<10; ++kc){
        bf16x8 hf = *(const bf16x8*)(hcur + l15*640 + (((kc*64) + lk*16) ^ ((l15&7)<<4)));
        #pragma unroll
        for (int g=0; g<4; ++g)
          acc[g] = __builtin_amdgcn_mfma_f32_16x16x32_bf16(
                     *(const bf16x8*)&wl[w][g][kc][lane*8], hf, acc[g], 0, 0, 0);
      }
      ACT_PUB(acc, cL, jL)
    }
#undef ACT_PUB
    __syncthreads();   // h(t) complete in hnxt before next step's reads
  }
}

// ---------------- fused log_softmax (in-place on d_out) + masked NLL ----------------
__global__ __launch_bounds__(256) void lsm_loss(float* __restrict__ out, const int* __restrict__ zh,
                                                float* __restrict__ lacc){
  int row = blockIdx.x;
  int tid = threadIdx.x;
  __shared__ float buf[ZHV];
  __shared__ float red[8];
  float* p = out + (size_t)row*ZHV;
  float m = -1e30f;
  for (int i=tid; i<ZHV; i+=256){ float v = p[i]; buf[i] = v; m = fmaxf(m, v); }
  for (int off=32; off; off>>=1) m = fmaxf(m, __shfl_xor(m, off));
  if ((tid&63)==0) red[tid>>6] = m;
  __syncthreads();
  m = fmaxf(fmaxf(red[0],red[1]), fmaxf(red[2],red[3]));
  float s = 0.f;
  for (int i=tid; i<ZHV; i+=256) s += __expf(buf[i]-m);
  for (int off=32; off; off>>=1) s += __shfl_xor(s, off);
  if ((tid&63)==0) red[4+(tid>>6)] = s;
  __syncthreads();
  s = red[4]+red[5]+red[6]+red[7];
  float lse = m + __logf(s);
  for (int i=tid; i<ZHV; i+=256) p[i] = buf[i] - lse;
  if (tid == 0){
    int b = row / SDEC, t = row - b*SDEC;
    int tgt = zh[b*SENC + t + 1];
    if (tgt != 0){
      atomicAdd(&lacc[0], -(buf[tgt] - lse));
      atomicAdd(&lacc[1], 1.0f);
    }
  }
}

__global__ void fin_loss(float* out, const float* lacc){
  out[(size_t)DROWS*ZHV] = lacc[0]/lacc[1];
}

// ---------------- host ----------------
extern "C" void kernel_launch(void* const* d_in, const int* in_sizes, int n_in,
                              void* d_out, int out_size, void* d_ws, size_t ws_size,
                              hipStream_t stream){
  const int*   en_in   = (const int*)d_in[0];
  const int*   zh_in   = (const int*)d_in[1];
  const float* en_emb  = (const float*)d_in[2];
  const float* zh_emb  = (const float*)d_in[3];
  const float* enc_Wih = (const float*)d_in[4];
  const float* enc_Whh = (const float*)d_in[5];
  const float* enc_b   = (const float*)d_in[6];
  const float* dec_Wih = (const float*)d_in[7];
  const float* dec_Whh = (const float*)d_in[8];
  const float* dec_b   = (const float*)d_in[9];
  const float* fc_W    = (const float*)d_in[10];
  const float* fc_b    = (const float*)d_in[11];
  float* out = (float*)d_out;
  char* ws = (char*)d_ws;

  size_t o = 0;
  auto alloc = [&](size_t b){ size_t r = o; o = (o + b + 255) & ~(size_t)255; return r; };
  size_t wa[4], wih[4];
  for (int i=0;i<4;i++) wa[i]  = alloc((size_t)20*4*10*512*2); // MFMA A-frag Whh bf16
  for (int i=0;i<4;i++) wih[i] = alloc((size_t)1280*KPAD*2);   // Wih as B operand
  size_t fcw  = alloc((size_t)12032*KPAD*2);
  size_t xen  = alloc((size_t)MPAD*KPAD*2);
  size_t xl1e = alloc((size_t)MPAD*KPAD*2);
  size_t xzh  = alloc((size_t)MPAD*KPAD*2);
  size_t xl1d = alloc((size_t)MPAD*KPAD*2);
  size_t xl2d = alloc((size_t)MPAD*KPAD*2);
  size_t xih  = alloc(((size_t)MPAD*NG + 64)*4);   // +64 floats: padded-slice overread
  size_t hfin = alloc((size_t)2*NB*EDIM*4);
  size_t cfin = alloc((size_t)2*NB*EDIM*4);
  size_t hz   = alloc((size_t)NB*EDIM*4 + 64);
  size_t lac  = alloc(256);
  size_t used = o;
  if (ws_size < used) return;  // fail loudly (output stays poisoned)

  zero_kernel<<<2048,256,0,stream>>>((float4*)ws, (long)(used/16));

  for (int l=0;l<2;l++){
    build_wa<<<1600,256,0,stream>>>(enc_Whh + (size_t)l*NG*EDIM, (u16*)(ws+wa[l]));
    build_wa<<<1600,256,0,stream>>>(dec_Whh + (size_t)l*NG*EDIM, (u16*)(ws+wa[2+l]));
    build_b<<<1407,256,0,stream>>>(enc_Wih + (size_t)l*NG*EDIM, (u16*)(ws+wih[l]),   NG);
    build_b<<<1407,256,0,stream>>>(dec_Wih + (size_t)l*NG*EDIM, (u16*)(ws+wih[2+l]), NG);
  }
  build_b<<<(ZHV*EDIM+255)/256,256,0,stream>>>(fc_W, (u16*)(ws+fcw), ZHV);
  embed_en<<<(MPAD*EDIM+255)/256,256,0,stream>>>(en_in, en_emb, (u16*)(ws+xen));
  embed_zh<<<(DROWS*EDIM+255)/256,256,0,stream>>>(zh_in, zh_emb, (u16*)(ws+xzh));

  float* XIH = (float*)(ws+xih);
  float* LAC = (float*)(ws+lac);
  float* HF  = (float*)(ws+hfin);
  float* CF  = (float*)(ws+cfin);
  float* HZ  = (float*)(ws+hz);

  // encoder layer 1  (LSTM bias folded into XIH via gemm bias)
  gemm_nt<<<dim3(10,32),256,0,stream>>>((u16*)(ws+xen), (u16*)(ws+wih[0]), XIH, NG, MPAD, NG, enc_b);
  recur_mix<<<4,512,0,stream>>>(XIH, (u16*)(ws+wa[0]), HZ, HZ, (u16*)(ws+xl1e), HF, CF, SENC);
  // encoder layer 2 (hidden sequence unused; only finals kept)
  gemm_nt<<<dim3(10,32),256,0,stream>>>((u16*)(ws+xl1e), (u16*)(ws+wih[1]), XIH, NG, MPAD, NG, enc_b+NG);
  recur_mix<<<4,512,0,stream>>>(XIH, (u16*)(ws+wa[1]), HZ, HZ, nullptr, HF+NB*EDIM, CF+NB*EDIM, SENC);
  // decoder layer 1
  gemm_nt<<<dim3(10,32),256,0,stream>>>((u16*)(ws+xzh), (u16*)(ws+wih[2]), XIH, NG, MPAD, NG, dec_b);
  recur_mix<<<4,512,0,stream>>>(XIH, (u16*)(ws+wa[2]), HF, CF, (u16*)(ws+xl1d), nullptr, nullptr, SDEC);
  // decoder layer 2
  gemm_nt<<<dim3(10,32),256,0,stream>>>((u16*)(ws+xl1d), (u16*)(ws+wih[3]), XIH, NG, MPAD, NG, dec_b+NG);
  recur_mix<<<4,512,0,stream>>>(XIH, (u16*)(ws+wa[3]), HF+NB*EDIM, CF+NB*EDIM, (u16*)(ws+xl2d), nullptr, nullptr, SDEC);
  // FC head -> logits straight into d_out
  gemm_nt<<<dim3(94,32),256,0,stream>>>((u16*)(ws+xl2d), (u16*)(ws+fcw), out, ZHV, DROWS, ZHV, fc_b);
  // in-place log_softmax + masked NLL
  lsm_loss<<<DROWS,256,0,stream>>>(out, zh_in, LAC);
  fin_loss<<<1,1,0,stream>>>(out, LAC);
}